// Round 17
// baseline (26.126 us; speedup 1.0000x reference)
//
#include <hip/hip_runtime.h>

// SemiPool2d max-plus: out[b,c,p,q] = max_{i<7,j<7}( x[b,c,2p+i,2q+j] + w[c,i,j] )
// x: (8,64,224,224) f32, w: (1,64,7,7) f32, out: (8,64,109,109) f32
//
// R16 structure with PBAND=8: 21-row input band = 18.8 KB LDS ->
// 8 blocks/CU resident (150.5 KB), 32 waves/CU (100% occupancy) — the
// endpoint of the residency axis (R11->R15->R16 trend: 27.1->26.3->25.5).
// Staging via global_load_lds (zero-VGPR DMA), vmcnt(0)+barrier, weights in
// SGPRs, conflict-free stride-2 column compute, coalesced stores.
// 14 bands (band 13 clamps to p0=101; overlap rows rewritten with identical
// values, benign). Per thread: 4 outputs, 13 LDS rows; even ph split.

#define HH 224
#define WW 224
#define HO 109
#define WO 109
#define CC 64
#define PBAND 8
#define NBANDS 14
#define INROWS 21                   // 2*8+5
#define LDSF (INROWS*WW)            // 4704 floats = 18816 B
#define WCH 294                     // 16B chunks per wave = 4704/4/4
#define NSTG 5                      // 4 full + 38-lane

__global__ __launch_bounds__(256) void semipool_kernel(
    const float* __restrict__ x,
    const float* __restrict__ w,
    float* __restrict__ out)
{
    __shared__ float smem[LDSF];

    const int tid  = threadIdx.x;
    const int wv   = tid >> 6;
    const int lane = tid & 63;
    const int band = blockIdx.x >> 9;        // 0..13
    const int bc   = blockIdx.x & 511;       // scalar

    int p0 = band * PBAND;
    if (p0 > HO - PBAND) p0 = HO - PBAND;    // band 13 -> 101
    const int row0 = 2 * p0;

    // ---- stage 21x224 floats into LDS (wave-blocked, 5 instrs/wave) ----
    const float* src = x + (bc * HH + row0) * WW;
#pragma unroll
    for (int it = 0; it < NSTG; ++it) {
        int off = it * 64 + lane;
        if (off < WCH) {
            int c = wv * WCH + off;
            __builtin_amdgcn_global_load_lds(
                (const __attribute__((address_space(1))) void*)(src + 4 * c),
                (__attribute__((address_space(3))) void*)(smem + 4 * c),
                16, 0, 0);
        }
    }

    // 49 channel weights -> SGPRs (uniform address; lgkmcnt, not vmcnt)
    const float* __restrict__ wp = w + (bc & (CC - 1)) * 49;
    float wr[49];
#pragma unroll
    for (int k = 0; k < 49; ++k) wr[k] = wp[k];

    asm volatile("s_waitcnt vmcnt(0)" ::: "memory");
    __builtin_amdgcn_sched_barrier(0);
    __builtin_amdgcn_s_barrier();            // band fully staged
    __builtin_amdgcn_sched_barrier(0);

    // ---- compute: thread = (q, p-half); 4 outputs in a column ----
    int q = tid & 127; if (q > WO - 1) q = WO - 1;   // dups benign
    const int ph   = tid >> 7;                       // 0/1 (wave-uniform)
    const int colb = 2 * q;
    const int rbase = 8 * ph;                // ph0: inputs 0..12, ph1: 8..20

    float acc[4];
#pragma unroll
    for (int a = 0; a < 4; ++a) acc[a] = -1e30f;

#pragma unroll
    for (int r = 0; r < 13; ++r) {           // local input rows for thread
        const float* lr = smem + (rbase + r) * WW + colb;
        float xr[8];
#pragma unroll
        for (int k = 0; k < 4; ++k) {
            float2 v = *reinterpret_cast<const float2*>(lr + 2 * k);
            xr[2 * k]     = v.x;
            xr[2 * k + 1] = v.y;
        }
#pragma unroll
        for (int pp = 0; pp < 4; ++pp) {
            int i = r - 2 * pp;              // compile-time after unroll
            if (i >= 0 && i < 7) {
                float s0 = xr[0] + wr[i * 7 + 0];
                float s1 = xr[1] + wr[i * 7 + 1];
                float s2 = xr[2] + wr[i * 7 + 2];
                float s3 = xr[3] + wr[i * 7 + 3];
                float s4 = xr[4] + wr[i * 7 + 4];
                float s5 = xr[5] + wr[i * 7 + 5];
                float s6 = xr[6] + wr[i * 7 + 6];
                float t0 = fmaxf(fmaxf(s0, s1), s2);   // v_max3
                float t1 = fmaxf(fmaxf(s3, s4), s5);   // v_max3
                float t2 = fmaxf(fmaxf(t0, t1), s6);   // v_max3
                acc[pp] = fmaxf(acc[pp], t2);
            }
        }
    }

    // outputs p0 + 4*ph + pp  (even split, no duplicated row)
    float* __restrict__ orow = out + (bc * HO + p0 + 4 * ph) * WO + q;
#pragma unroll
    for (int pp = 0; pp < 4; ++pp)
        orow[pp * WO] = acc[pp];
}

extern "C" void kernel_launch(void* const* d_in, const int* in_sizes, int n_in,
                              void* d_out, int out_size, void* d_ws, size_t ws_size,
                              hipStream_t stream) {
    const float* x = (const float*)d_in[0];
    const float* w = (const float*)d_in[1];
    float* out = (float*)d_out;

    semipool_kernel<<<NBANDS * 512, 256, 0, stream>>>(x, w, out);
}

// Round 18
// 25.472 us; speedup vs baseline: 1.0257x; 1.0257x over previous
//
#include <hip/hip_runtime.h>

// SemiPool2d max-plus: out[b,c,p,q] = max_{i<7,j<7}( x[b,c,2p+i,2q+j] + w[c,i,j] )
// x: (8,64,224,224) f32, w: (1,64,7,7) f32, out: (8,64,109,109) f32
//
// R16 (best: PBAND=10, 22.4KB LDS, 7 blocks/CU, 25.5us) + bijective
// XCD-chunked grid swizzle: work = bc*11 + band (channel-major), 5632
// blocks = 8 XCDs x 704 exactly; each XCD owns 64 channels x 11 bands
// contiguously -> a channel's consecutive bands run nearby in time on the
// same XCD, so the 5-row inter-band halo (23% of staged bytes) hits that
// XCD's L2 instead of L3, and phase bunching across co-resident blocks
// decorrelates. Kernel body identical to R16.

#define HH 224
#define WW 224
#define HO 109
#define WO 109
#define CC 64
#define PBAND 10
#define NBANDS 11
#define INROWS 25                   // 2*10+5
#define LDSF (INROWS*WW)            // 5600 floats = 22400 B
#define WCH 350                     // 16B chunks per wave = 5600/4/4
#define NSTG 6                      // 5 full + 30-lane
#define NWG (NBANDS*512)            // 5632 = 8 * 704
#define PER_XCD (NWG/8)             // 704

__global__ __launch_bounds__(256) void semipool_kernel(
    const float* __restrict__ x,
    const float* __restrict__ w,
    float* __restrict__ out)
{
    __shared__ float smem[LDSF];

    const int tid  = threadIdx.x;
    const int wv   = tid >> 6;
    const int lane = tid & 63;

    // bijective XCD-chunked swizzle (nwg % 8 == 0): consecutive hardware
    // blocks round-robin XCDs; give each XCD a contiguous channel-major
    // slice of the work list.
    const int bid  = blockIdx.x;
    const int wkid = (bid & 7) * PER_XCD + (bid >> 3);   // 0..5631
    const int bc   = wkid / NBANDS;                      // 0..511 (scalar)
    const int band = wkid - bc * NBANDS;                 // 0..10

    int p0 = band * PBAND;
    if (p0 > HO - PBAND) p0 = HO - PBAND;    // band 10 -> 99
    const int row0 = 2 * p0;

    // ---- stage 25x224 floats into LDS (wave-blocked, 6 instrs/wave) ----
    const float* src = x + (bc * HH + row0) * WW;
#pragma unroll
    for (int it = 0; it < NSTG; ++it) {
        int off = it * 64 + lane;
        if (off < WCH) {
            int c = wv * WCH + off;
            __builtin_amdgcn_global_load_lds(
                (const __attribute__((address_space(1))) void*)(src + 4 * c),
                (__attribute__((address_space(3))) void*)(smem + 4 * c),
                16, 0, 0);
        }
    }

    // 49 channel weights -> SGPRs (uniform address; lgkmcnt, not vmcnt)
    const float* __restrict__ wp = w + (bc & (CC - 1)) * 49;
    float wr[49];
#pragma unroll
    for (int k = 0; k < 49; ++k) wr[k] = wp[k];

    asm volatile("s_waitcnt vmcnt(0)" ::: "memory");
    __builtin_amdgcn_sched_barrier(0);
    __builtin_amdgcn_s_barrier();            // band fully staged
    __builtin_amdgcn_sched_barrier(0);

    // ---- compute: thread = (q, p-half); 5 outputs in a column ----
    int q = tid & 127; if (q > WO - 1) q = WO - 1;   // dups benign
    const int ph   = tid >> 7;                       // 0/1 (wave-uniform)
    const int colb = 2 * q;
    const int rbase = 10 * ph;               // ph0: inputs 0..14, ph1: 10..24

    float acc[5];
#pragma unroll
    for (int a = 0; a < 5; ++a) acc[a] = -1e30f;

#pragma unroll
    for (int r = 0; r < 15; ++r) {           // local input rows for thread
        const float* lr = smem + (rbase + r) * WW + colb;
        float xr[8];
#pragma unroll
        for (int k = 0; k < 4; ++k) {
            float2 v = *reinterpret_cast<const float2*>(lr + 2 * k);
            xr[2 * k]     = v.x;
            xr[2 * k + 1] = v.y;
        }
#pragma unroll
        for (int pp = 0; pp < 5; ++pp) {
            int i = r - 2 * pp;              // compile-time after unroll
            if (i >= 0 && i < 7) {
                float s0 = xr[0] + wr[i * 7 + 0];
                float s1 = xr[1] + wr[i * 7 + 1];
                float s2 = xr[2] + wr[i * 7 + 2];
                float s3 = xr[3] + wr[i * 7 + 3];
                float s4 = xr[4] + wr[i * 7 + 4];
                float s5 = xr[5] + wr[i * 7 + 5];
                float s6 = xr[6] + wr[i * 7 + 6];
                float t0 = fmaxf(fmaxf(s0, s1), s2);   // v_max3
                float t1 = fmaxf(fmaxf(s3, s4), s5);   // v_max3
                float t2 = fmaxf(fmaxf(t0, t1), s6);   // v_max3
                acc[pp] = fmaxf(acc[pp], t2);
            }
        }
    }

    // outputs p0 + 5*ph + pp  (even split, no duplicated row)
    float* __restrict__ orow = out + (bc * HO + p0 + 5 * ph) * WO + q;
#pragma unroll
    for (int pp = 0; pp < 5; ++pp)
        orow[pp * WO] = acc[pp];
}

extern "C" void kernel_launch(void* const* d_in, const int* in_sizes, int n_in,
                              void* d_out, int out_size, void* d_ws, size_t ws_size,
                              hipStream_t stream) {
    const float* x = (const float*)d_in[0];
    const float* w = (const float*)d_in[1];
    float* out = (float*)d_out;

    semipool_kernel<<<NWG, 256, 0, stream>>>(x, w, out);
}